// Round 10
// baseline (462.928 us; speedup 1.0000x reference)
//
#include <hip/hip_runtime.h>
#include <hip/hip_bf16.h>

#define N_NODES 200000
#define N_EDGES 1200000
#define IN_DIM  128
#define HID     64
#define NGRAPH  1024
#define NCLS    6
#define BN_EPS  1e-5f

#define TILE_N   64
#define ZS       68          // Ztmp row stride (floats); 272B = 17 banks shift, 2-way max
#define ECAP     1024

// ---- binned CSR build ----
#define NBKT   128           // dst-range buckets
#define BRANGE 1568          // nodes per bucket (128*1568 = 200704 >= N)
#define BCAP   12288         // per-bucket edge capacity (mean 9408, sigma ~97)
#define EPB    2048          // edges per bin block (r9: halved -> 2.3 blocks/CU)
#define NB_BIN ((N_EDGES + EPB - 1) / EPB)   // 586
#define NB_SETUP 325         // setup blocks before the bin range
// packed ebin entry: src (18b) | dstLocal (11b) << 18

// 16B-slot XOR swizzle for A-frag LDS
#define SWZ(s) ((s) ^ (((s) >> 4) & 3))

typedef short bf16x8 __attribute__((ext_vector_type(8)));
typedef float f32x4  __attribute__((ext_vector_type(4)));
#define MFMA16(a,b,c) __builtin_amdgcn_mfma_f32_16x16x32_bf16((a),(b),(c),0,0,0)

template<bool V> struct BoolC { static constexpr bool value = V; };

__device__ __forceinline__ unsigned short f2bf(float f) {
    union { __hip_bfloat16 h; unsigned short u; } v; v.h = __float2bfloat16(f); return v.u;
}
__device__ __forceinline__ float bfbits2f(unsigned short u) {
    union { unsigned int i; float f; } v; v.i = ((unsigned int)u) << 16; return v.f;
}
// f32x4 -> (hi bf16x4, lo bf16x4) packed as uint2 each
__device__ __forceinline__ void cvt4(const f32x4& x, uint2& hi, uint2& lo) {
    const unsigned short h0 = f2bf(x[0]), h1 = f2bf(x[1]), h2 = f2bf(x[2]), h3 = f2bf(x[3]);
    hi.x = (unsigned)h0 | ((unsigned)h1 << 16);
    hi.y = (unsigned)h2 | ((unsigned)h3 << 16);
    const unsigned short l0 = f2bf(x[0] - bfbits2f(h0)), l1 = f2bf(x[1] - bfbits2f(h1));
    const unsigned short l2 = f2bf(x[2] - bfbits2f(h2)), l3 = f2bf(x[3] - bfbits2f(h3));
    lo.x = (unsigned)l0 | ((unsigned)l1 << 16);
    lo.y = (unsigned)l2 | ((unsigned)l3 << 16);
}

// ===========================================================================
// Setup + bin kernel. Blocks 0..63 prep_emb, 64..255 prep_fc, 256..260
// graph_offs, 261..324 pooled-zero, 325.. edge binning (586 blocks, 8 edges/
// thread). gcnt zeroed by a preceding 512 B memset.
// ===========================================================================
__global__ __launch_bounds__(256) void setup_bin_kernel(
    const float* __restrict__ emb_w, unsigned short* __restrict__ wpe,
    const float* __restrict__ fc1, const float* __restrict__ fc2,
    unsigned short* __restrict__ wpf,
    const int* __restrict__ batch, int* __restrict__ goffs,
    int* __restrict__ gcnt, float* __restrict__ pooled,
    const int* __restrict__ src, const int* __restrict__ dst,
    unsigned* __restrict__ ebin)
{
    __shared__ int hist[NBKT];
    __shared__ int basis[NBKT];
    const int b = blockIdx.x, t = threadIdx.x;
    if (b >= NB_SETUP) {
        // ---- bin path ----
        const int base = (b - NB_SETUP) * EPB;
        if (t < NBKT) hist[t] = 0;
        __syncthreads();
        int sv[8], dv[8];
        #pragma unroll
        for (int i = 0; i < 8; i++) {
            const int e = base + t + i * 256;
            if (e < N_EDGES) {
                sv[i] = __builtin_nontemporal_load(&src[e]);
                dv[i] = __builtin_nontemporal_load(&dst[e]);
                atomicAdd(&hist[dv[i] / BRANGE], 1);
            } else { sv[i] = -1; dv[i] = -1; }
        }
        __syncthreads();
        if (t < NBKT) { basis[t] = atomicAdd(&gcnt[t], hist[t]); hist[t] = 0; }
        __syncthreads();
        #pragma unroll
        for (int i = 0; i < 8; i++) {
            if (dv[i] >= 0) {
                const int bb = dv[i] / BRANGE;
                const int dl = dv[i] - bb * BRANGE;
                const int pos = basis[bb] + atomicAdd(&hist[bb], 1);
                __builtin_nontemporal_store(
                    (unsigned)sv[i] | ((unsigned)dl << 18),
                    &ebin[(size_t)bb * BCAP + pos]);
            }
        }
        return;
    }
    if (b < 64) {
        const int idx = b * 256 + t;                     // [ct2][s2][p1][l6][j3]
        const int j = idx & 7, l = (idx >> 3) & 63;
        const int plane = (idx >> 9) & 1, s = (idx >> 10) & 3, ct = (idx >> 12) & 3;
        const int n = ct * 16 + (l & 15);
        const int k = s * 32 + (l >> 4) * 8 + j;
        const float f = emb_w[k * 64 + n];
        const unsigned short hb = f2bf(f);
        wpe[idx] = plane ? f2bf(f - bfbits2f(hb)) : hb;
    } else if (b < 256) {
        const int idx = (b - 64) * 256 + t;              // [layer][g][ct2][s1][p1][l6][j3]
        const int j = idx & 7, l = (idx >> 3) & 63;
        const int plane = (idx >> 9) & 1, s = (idx >> 10) & 1, ct = (idx >> 11) & 3;
        const int g = (idx >> 13) & 1, layer = idx >> 14;
        const int n = ct * 16 + (l & 15);
        const int k = s * 32 + (l >> 4) * 8 + j;
        const float* W = g ? fc2 : fc1;
        const float f = W[(layer * 64 + k) * 64 + n];
        const unsigned short hb = f2bf(f);
        wpf[idx] = plane ? f2bf(f - bfbits2f(hb)) : hb;
    } else if (b < 261) {
        const int g = (b - 256) * 256 + t;
        if (g > NGRAPH) return;
        if (g == NGRAPH) { goffs[NGRAPH] = N_NODES; return; }
        int lo = 0, hi = N_NODES;
        while (lo < hi) {
            const int mid = (lo + hi) >> 1;
            if (batch[mid] < g) lo = mid + 1; else hi = mid;
        }
        goffs[g] = lo;
    } else {
        const int idx = (b - 261) * 256 + t;             // 16384 float4s
        const f32x4 z = {0.f, 0.f, 0.f, 0.f};
        *(f32x4*)(pooled + (size_t)idx * 4) = z;
    }
}

// ===========================================================================
// Embed: h0 = relu(bn(x @ W + b)) via split-bf16 MFMA.
// x NT-read (true stream); h0 store NORMAL (layer-1 gather prefill).
// ===========================================================================
__global__ __launch_bounds__(256) void embed_kernel(
    const float* __restrict__ x, const unsigned short* __restrict__ wpe,
    const float* __restrict__ bias,
    const float* __restrict__ bn_g, const float* __restrict__ bn_b,
    const float* __restrict__ bn_m, const float* __restrict__ bn_v,
    float* __restrict__ h)
{
    __shared__ __align__(16) float Ush[8192];                  // 32 KB union
    __shared__ float BNs[128];
    short* Abuf = (short*)Ush;
    float* Ztmp = Ush;
    const int t = threadIdx.x, lane = t & 63, w = t >> 6;
    const int base = blockIdx.x * TILE_N;

    if (t < 64) {
        const float s = bn_g[t] * rsqrtf(bn_v[t] + BN_EPS);
        BNs[t] = s;
        BNs[64 + t] = bias[t] * s + bn_b[t] - bn_m[t] * s;
    }
    // stage + hi/lo convert x tile into A-frag order (swizzled slots)
    #pragma unroll
    for (int i = 0; i < 8; i++) {
        const int idx = t + i * 256;                 // 0..2047
        const int n = idx >> 5, k4 = idx & 31;
        const f32x4 v = __builtin_nontemporal_load(
            (const f32x4*)(x + (size_t)(base + n) * IN_DIM + k4 * 4));
        uint2 hi, lo; cvt4(v, hi, lo);
        const int s = k4 >> 3, lc = (n & 15) + 16 * ((k4 >> 1) & 3);
        const int half = k4 & 1, wm = n >> 4;
        const int sl0 = ((wm * 4 + s) * 2 + 0) * 64 + lc;
        const int sl1 = ((wm * 4 + s) * 2 + 1) * 64 + lc;
        *(uint2*)&Abuf[SWZ(sl0) * 8 + half * 4] = hi;
        *(uint2*)&Abuf[SWZ(sl1) * 8 + half * 4] = lo;
    }
    __syncthreads();

    const bf16x8* A = (const bf16x8*)Abuf;
    const bf16x8* B = (const bf16x8*)wpe;
    bf16x8 ah[4], al[4];
    #pragma unroll
    for (int s = 0; s < 4; s++) {
        ah[s] = A[SWZ(((w * 4 + s) * 2 + 0) * 64 + lane)];
        al[s] = A[SWZ(((w * 4 + s) * 2 + 1) * 64 + lane)];
    }
    __syncthreads();    // all frag reads done; Ztmp may overwrite Abuf
    const int q = lane >> 4, c = lane & 15;
    #pragma unroll
    for (int ct = 0; ct < 4; ct++) {
        f32x4 acc = {0.f, 0.f, 0.f, 0.f};
        #pragma unroll
        for (int s = 0; s < 4; s++) {
            const bf16x8 bh = B[(ct << 9) + (s << 7) + lane];
            const bf16x8 bl = B[(ct << 9) + (s << 7) + 64 + lane];
            acc = MFMA16(ah[s], bh, acc);
            acc = MFMA16(ah[s], bl, acc);
            acc = MFMA16(al[s], bh, acc);
        }
        const int n = ct * 16 + c;
        const float sc = BNs[n], sh = BNs[64 + n];
        #pragma unroll
        for (int r = 0; r < 4; r++)
            Ztmp[(w * 16 + q * 4 + r) * ZS + n] = fmaxf(acc[r] * sc + sh, 0.f);
    }
    __syncthreads();
    #pragma unroll
    for (int i = 0; i < 4; i++) {
        const int idx = t + i * 256, n = idx >> 4, k4 = idx & 15;
        *(f32x4*)(h + (size_t)(base + n) * HID + k4 * 4) =
            *(const f32x4*)(&Ztmp[n * ZS + k4 * 4]);
    }
}

// ===========================================================================
// Fused offs+scatter: one 1024-thread block per bucket (r9: was 512 — only
// 1/4 of the machine and 19 strided iterations; 1024 halves every phase).
// Stage packed edges in LDS, histogram, 2-level scan -> offs, rewrite hist
// as absolute cursors, scatter to csr straight from LDS. LDS 58.6 KB.
// ===========================================================================
__global__ __launch_bounds__(1024) void offs_scatter_kernel(
    const int* __restrict__ gcnt, const unsigned* __restrict__ ebin,
    int* __restrict__ offs, int* __restrict__ csr_src)
{
    __shared__ unsigned eb[BCAP];          // 49152 B
    __shared__ int hist[BRANGE];           // 6272 B
    __shared__ int bscan[NBKT];            // 512 B
    __shared__ int pscan[1024];            // 4096 B
    const int b = blockIdx.x, t = threadIdx.x;
    const int cnt = gcnt[b];
    for (int i = t; i < cnt; i += 1024)
        eb[i] = __builtin_nontemporal_load(&ebin[(size_t)b * BCAP + i]);
    for (int i = t; i < BRANGE; i += 1024) hist[i] = 0;
    if (t < NBKT) bscan[t] = gcnt[t];
    __syncthreads();
    for (int i = t; i < cnt; i += 1024)
        atomicAdd(&hist[eb[i] >> 18], 1);
    __syncthreads();
    // inclusive scan over the 128 bucket counts
    for (int off = 1; off < NBKT; off <<= 1) {
        const int u = (t >= off && t < NBKT) ? bscan[t - off] : 0;
        __syncthreads();
        if (t < NBKT) bscan[t] += u;
        __syncthreads();
    }
    const int bucketBase = (b == 0) ? 0 : bscan[b - 1];
    // per-thread chunk of 2 nodes, then 1024-wide scan
    const int i0 = t * 2;
    const int h0v = (i0 + 0 < BRANGE) ? hist[i0 + 0] : 0;
    const int h1v = (i0 + 1 < BRANGE) ? hist[i0 + 1] : 0;
    const int ts = h0v + h1v;
    pscan[t] = ts;
    __syncthreads();
    for (int off = 1; off < 1024; off <<= 1) {
        const int u = (t >= off) ? pscan[t - off] : 0;
        __syncthreads();
        pscan[t] += u;
        __syncthreads();
    }
    const int excl = pscan[t] - ts + bucketBase;
    const int r0 = b * BRANGE;
    // write offs + rewrite hist in-place as absolute cursors
    if (i0 + 0 < BRANGE) {
        if (r0 + i0 + 0 < N_NODES) offs[r0 + i0 + 0] = excl;
        hist[i0 + 0] = excl;
    }
    if (i0 + 1 < BRANGE) {
        if (r0 + i0 + 1 < N_NODES) offs[r0 + i0 + 1] = excl + h0v;
        hist[i0 + 1] = excl + h0v;
    }
    if (b == NBKT - 1 && t == 0) offs[N_NODES] = N_EDGES;
    __syncthreads();
    // scatter from LDS; cursors are absolute csr positions
    for (int i = t; i < cnt; i += 1024) {
        const unsigned e = eb[i];
        const int pos = atomicAdd(&hist[e >> 18], 1);
        csr_src[pos] = (int)(e & 0x3FFFFu);
    }
}

// ===========================================================================
// Fused GIN layer. h accesses CACHED (h rows carry gather reuse). allLds
// branch removes the per-edge predicated csr[] load. 6 blocks/CU. POOL=true
// (last layer): pool directly from Ztmp via atomics, skip hout store.
// UNCHANGED since r8 — control group (63.2 us, FETCH 167 MB, WRITE 50 MB).
// ===========================================================================
template<bool POOL>
__global__ __launch_bounds__(256, 6) void agg_mlp_kernel(
    const float* __restrict__ hin, float* __restrict__ hout,
    const int* __restrict__ offs, const int* __restrict__ csr,
    const int* __restrict__ batch, float* __restrict__ pooled,
    const unsigned short* __restrict__ wp1, const unsigned short* __restrict__ wp2,
    const float* __restrict__ b1, const float* __restrict__ g1,
    const float* __restrict__ bb1, const float* __restrict__ m1, const float* __restrict__ v1,
    const float* __restrict__ b2, const float* __restrict__ g2,
    const float* __restrict__ bb2, const float* __restrict__ m2, const float* __restrict__ v2)
{
    __shared__ __align__(16) float Ush[TILE_N * ZS];           // 17408 B union
    __shared__ int   OF[TILE_N + 1];
    __shared__ int   EIDX[ECAP];                               // 4 KB
    __shared__ float BNs[256];
    __shared__ int   GID[TILE_N];
    short* Abuf = (short*)Ush;
    float* Ztmp = Ush;
    const int t = threadIdx.x, lane = t & 63, w = t >> 6;
    const int sub = lane >> 4, cq = lane & 15;
    const int base = blockIdx.x * TILE_N;

    if (t < 64) {
        const float sa = g1[t] * rsqrtf(v1[t] + BN_EPS);
        BNs[t] = sa; BNs[64 + t] = b1[t] * sa + bb1[t] - m1[t] * sa;
        const float sb = g2[t] * rsqrtf(v2[t] + BN_EPS);
        BNs[128 + t] = sb; BNs[192 + t] = b2[t] * sb + bb2[t] - m2[t] * sb;
        if (POOL) GID[t] = batch[base + t];
    }
    if (t <= TILE_N) OF[t] = offs[base + t];
    const int segStart = offs[base];
    const int segEnd   = offs[base + TILE_N];
    for (int i = t; i < segEnd - segStart; i += 256)
        if (i < ECAP) EIDX[i] = csr[segStart + i];
    __syncthreads();

    // gather -> A-frag hi/lo writes (swizzled slots)
    // two chains (A,B) advance together: 8 independent loads per wait
    const float* __restrict__ hc = hin + cq * 4;
    const bool allLds = (segEnd - segStart) <= ECAP;   // true for ~all tiles

    auto gather_pass = [&](auto ldsTag) {
        constexpr bool LDSONLY = decltype(ldsTag)::value;
        #pragma unroll
        for (int pp = 0; pp < 2; pp++) {
            const int mlA = (pp * 2 + 0) * 4 + sub;
            const int mlB = (pp * 2 + 1) * 4 + sub;
            const int nlA = w * 16 + mlA, nlB = w * 16 + mlB;
            int eA = OF[nlA]; const int eA1 = OF[nlA + 1];
            int eB = OF[nlB]; const int eB1 = OF[nlB + 1];
            // clamp targets stay inside [segStart, segEnd): deg-0-safe
            const int eAm = (eA1 - 1 > segStart) ? eA1 - 1 : segStart;
            const int eBm = (eB1 - 1 > segStart) ? eB1 - 1 : segStart;
            f32x4 accA = *(const f32x4*)(hin + (size_t)(base + nlA) * HID + cq * 4);
            f32x4 accB = *(const f32x4*)(hin + (size_t)(base + nlB) * HID + cq * 4);
            while (eA < eA1 || eB < eB1) {
                int ia[4], ib[4];
                #pragma unroll
                for (int k = 0; k < 4; k++) {
                    const int ea = (eA + k < eAm) ? eA + k : eAm;
                    const int eb = (eB + k < eBm) ? eB + k : eBm;
                    const int la = ea - segStart, lb = eb - segStart;
                    if (LDSONLY) {
                        ia[k] = EIDX[la];
                        ib[k] = EIDX[lb];
                    } else {
                        ia[k] = (la < ECAP) ? EIDX[la] : csr[ea];
                        ib[k] = (lb < ECAP) ? EIDX[lb] : csr[eb];
                    }
                }
                f32x4 va[4], vb[4];
                #pragma unroll
                for (int k = 0; k < 4; k++) {
                    va[k] = *(const f32x4*)(hc + (size_t)ia[k] * HID);
                    vb[k] = *(const f32x4*)(hc + (size_t)ib[k] * HID);
                }
                #pragma unroll
                for (int k = 0; k < 4; k++) {
                    const float ma = (eA + k < eA1) ? 1.f : 0.f;
                    const float mb = (eB + k < eB1) ? 1.f : 0.f;
                    accA += va[k] * ma;
                    accB += vb[k] * mb;
                }
                eA += 4; eB += 4;
            }
            {
                uint2 hi, lo; cvt4(accA, hi, lo);
                const int s = cq >> 3, lc = mlA + 16 * ((cq >> 1) & 3), half = cq & 1;
                const int sl0 = ((w * 2 + s) * 2 + 0) * 64 + lc;
                const int sl1 = ((w * 2 + s) * 2 + 1) * 64 + lc;
                *(uint2*)&Abuf[SWZ(sl0) * 8 + half * 4] = hi;
                *(uint2*)&Abuf[SWZ(sl1) * 8 + half * 4] = lo;
            }
            {
                uint2 hi, lo; cvt4(accB, hi, lo);
                const int s = cq >> 3, lc = mlB + 16 * ((cq >> 1) & 3), half = cq & 1;
                const int sl0 = ((w * 2 + s) * 2 + 0) * 64 + lc;
                const int sl1 = ((w * 2 + s) * 2 + 1) * 64 + lc;
                *(uint2*)&Abuf[SWZ(sl0) * 8 + half * 4] = hi;
                *(uint2*)&Abuf[SWZ(sl1) * 8 + half * 4] = lo;
            }
        }
    };
    if (allLds) gather_pass(BoolC<true>{});
    else        gather_pass(BoolC<false>{});
    __syncthreads();

    const bf16x8* A = (const bf16x8*)Abuf;
    const int q = lane >> 4, c = lane & 15;

    // GEMM1
    {
        const bf16x8 a0h = A[SWZ(((w * 2 + 0) * 2 + 0) * 64 + lane)];
        const bf16x8 a0l = A[SWZ(((w * 2 + 0) * 2 + 1) * 64 + lane)];
        const bf16x8 a1h = A[SWZ(((w * 2 + 1) * 2 + 0) * 64 + lane)];
        const bf16x8 a1l = A[SWZ(((w * 2 + 1) * 2 + 1) * 64 + lane)];
        __syncthreads();    // frag reads done; Ztmp writes may alias Abuf
        const bf16x8* B = (const bf16x8*)wp1;
        #pragma unroll
        for (int ct = 0; ct < 4; ct++) {
            const bf16x8 b0h = B[(ct << 8) + lane];
            const bf16x8 b0l = B[(ct << 8) + 64 + lane];
            const bf16x8 b1h_ = B[(ct << 8) + 128 + lane];
            const bf16x8 b1l_ = B[(ct << 8) + 192 + lane];
            f32x4 acc = {0.f, 0.f, 0.f, 0.f};
            acc = MFMA16(a0h, b0h, acc);
            acc = MFMA16(a0h, b0l, acc);
            acc = MFMA16(a0l, b0h, acc);
            acc = MFMA16(a1h, b1h_, acc);
            acc = MFMA16(a1h, b1l_, acc);
            acc = MFMA16(a1l, b1h_, acc);
            const int n = ct * 16 + c;
            const float sc = BNs[n], sh = BNs[64 + n];
            #pragma unroll
            for (int r = 0; r < 4; r++)
                Ztmp[(w * 16 + q * 4 + r) * ZS + n] = fmaxf(acc[r] * sc + sh, 0.f);
        }
    }
    __syncthreads();    // Ztmp complete

    // re-split t1 into A-frags (register-staged: read all, barrier, write)
    {
        const int m = t >> 2;
        f32x4 vv[4];
        #pragma unroll
        for (int d = 0; d < 4; d++) {
            const int k4 = (t & 3) * 4 + d;
            vv[d] = *(const f32x4*)(&Ztmp[m * ZS + k4 * 4]);
        }
        __syncthreads();    // Ztmp reads done; A-frag writes may alias
        #pragma unroll
        for (int d = 0; d < 4; d++) {
            const int k4 = (t & 3) * 4 + d;
            uint2 hi, lo; cvt4(vv[d], hi, lo);
            const int s = k4 >> 3, lc = (m & 15) + 16 * ((k4 >> 1) & 3);
            const int half = k4 & 1, wm = m >> 4;
            const int sl0 = ((wm * 2 + s) * 2 + 0) * 64 + lc;
            const int sl1 = ((wm * 2 + s) * 2 + 1) * 64 + lc;
            *(uint2*)&Abuf[SWZ(sl0) * 8 + half * 4] = hi;
            *(uint2*)&Abuf[SWZ(sl1) * 8 + half * 4] = lo;
        }
    }
    __syncthreads();

    // GEMM2
    {
        const bf16x8 a0h = A[SWZ(((w * 2 + 0) * 2 + 0) * 64 + lane)];
        const bf16x8 a0l = A[SWZ(((w * 2 + 0) * 2 + 1) * 64 + lane)];
        const bf16x8 a1h = A[SWZ(((w * 2 + 1) * 2 + 0) * 64 + lane)];
        const bf16x8 a1l = A[SWZ(((w * 2 + 1) * 2 + 1) * 64 + lane)];
        __syncthreads();    // frag reads done; Ztmp writes may alias Abuf
        const bf16x8* B = (const bf16x8*)wp2;
        #pragma unroll
        for (int ct = 0; ct < 4; ct++) {
            const bf16x8 b0h = B[(ct << 8) + lane];
            const bf16x8 b0l = B[(ct << 8) + 64 + lane];
            const bf16x8 b1h_ = B[(ct << 8) + 128 + lane];
            const bf16x8 b1l_ = B[(ct << 8) + 192 + lane];
            f32x4 acc = {0.f, 0.f, 0.f, 0.f};
            acc = MFMA16(a0h, b0h, acc);
            acc = MFMA16(a0h, b0l, acc);
            acc = MFMA16(a0l, b0h, acc);
            acc = MFMA16(a1h, b1h_, acc);
            acc = MFMA16(a1h, b1l_, acc);
            acc = MFMA16(a1l, b1h_, acc);
            const int n = ct * 16 + c;
            const float sc = BNs[128 + n], sh = BNs[192 + n];
            #pragma unroll
            for (int r = 0; r < 4; r++)
                Ztmp[(w * 16 + q * 4 + r) * ZS + n] = fmaxf(acc[r] * sc + sh, 0.f);
        }
    }
    __syncthreads();

    if (POOL) {
        // pool directly from Ztmp: thread (c = t&63, rg = t>>6) run-sums its
        // 16 rows' column c grouped by graph id -> <=3 atomics per thread
        // into the L2-resident pooled[1024][64].
        const int cc = t & 63, rg = t >> 6;
        float run = 0.f;
        int cur = GID[rg * 16];
        #pragma unroll
        for (int r = 0; r < 16; r++) {
            const int row = rg * 16 + r;
            const int g = GID[row];
            if (g != cur) {
                atomicAdd(&pooled[(size_t)cur * HID + cc], run);
                run = 0.f; cur = g;
            }
            run += Ztmp[row * ZS + cc];
        }
        atomicAdd(&pooled[(size_t)cur * HID + cc], run);
    } else {
        #pragma unroll
        for (int i = 0; i < 4; i++) {
            const int idx = t + i * 256, n = idx >> 4, k4 = idx & 15;
            *(f32x4*)(hout + (size_t)(base + n) * HID + k4 * 4) =
                *(const f32x4*)(&Ztmp[n * ZS + k4 * 4]);
        }
    }
}

// ===========================================================================
// Classifier: cnt derived from goffs.
// ===========================================================================
__global__ __launch_bounds__(64) void cls_kernel(
    const float* __restrict__ pooled, const int* __restrict__ goffs,
    const float* __restrict__ w1, const float* __restrict__ b1,
    const float* __restrict__ w2, const float* __restrict__ b2,
    float* __restrict__ out)
{
    const int g = blockIdx.x;
    const int lane = threadIdx.x;
    const float c = (float)(goffs[g + 1] - goffs[g]);
    const float p = pooled[(size_t)g * HID + lane] / fmaxf(c, 1.f);
    float acc = (lane < 32) ? b1[lane] : 0.f;
    #pragma unroll
    for (int k = 0; k < 64; k++) {
        const float pk = __shfl(p, k, 64);
        if (lane < 32) acc += pk * w1[k * 32 + lane];
    }
    const float hmid = fmaxf(acc, 0.f);
    float acc2 = (lane < NCLS) ? b2[lane] : 0.f;
    #pragma unroll
    for (int k = 0; k < 32; k++) {
        const float hk = __shfl(hmid, k, 64);
        if (lane < NCLS) acc2 += hk * w2[k * NCLS + lane];
    }
    if (lane < NCLS) out[(size_t)g * NCLS + lane] = acc2;
}

// ===========================================================================
extern "C" void kernel_launch(void* const* d_in, const int* in_sizes, int n_in,
                              void* d_out, int out_size, void* d_ws, size_t ws_size,
                              hipStream_t stream) {
    const float* x     = (const float*)d_in[0];
    const int*   ei    = (const int*)d_in[1];
    const int*   batch = (const int*)d_in[2];
    const float* emb_w = (const float*)d_in[3];
    const float* emb_b = (const float*)d_in[4];
    const float* ibn_g = (const float*)d_in[5];
    const float* ibn_b = (const float*)d_in[6];
    const float* ibn_m = (const float*)d_in[7];
    const float* ibn_v = (const float*)d_in[8];
    const float* fc1_w = (const float*)d_in[9];
    const float* fc1_b = (const float*)d_in[10];
    const float* mbn_g = (const float*)d_in[11];
    const float* mbn_b = (const float*)d_in[12];
    const float* mbn_m = (const float*)d_in[13];
    const float* mbn_v = (const float*)d_in[14];
    const float* fc2_w = (const float*)d_in[15];
    const float* fc2_b = (const float*)d_in[16];
    const float* obn_g = (const float*)d_in[17];
    const float* obn_b = (const float*)d_in[18];
    const float* obn_m = (const float*)d_in[19];
    const float* obn_v = (const float*)d_in[20];
    const float* cls1w = (const float*)d_in[21];
    const float* cls1b = (const float*)d_in[22];
    const float* cls2w = (const float*)d_in[23];
    const float* cls2b = (const float*)d_in[24];

    float* h0     = (float*)d_ws;
    float* h1     = h0 + (size_t)N_NODES * HID;
    float* pooled = h1 + (size_t)N_NODES * HID;
    float* cnt    = pooled + NGRAPH * HID;            // unused (layout keep)
    int*   deg    = (int*)(cnt + NGRAPH);             // unused (layout keep)
    int*   offs   = deg + N_NODES;
    int*   bsum   = offs + (N_NODES + 1);             // unused
    int*   boff   = bsum + 256;                       // unused
    int*   csr    = boff + 256;
    unsigned short* wpe = (unsigned short*)(csr + N_EDGES);   // 16384
    unsigned short* wpf = wpe + 16384;                        // 49152
    int*   goffs  = (int*)(wpf + 49152);                      // NGRAPH+1
    int*   gcnt   = goffs + (NGRAPH + 1);                     // NBKT
    // ebin (packed u32) aliases h1: written by setup_bin, consumed by
    // offs_scatter BEFORE agg1 writes h1. 128*12288*4 B = 6.3 MB << 51.2 MB.
    unsigned* ebin = (unsigned*)h1;

    const int* src = ei;
    const int* dst = ei + N_EDGES;

    // gcnt must be zero before setup_bin's bin blocks (in-kernel zeroing
    // would race them).
    hipMemsetAsync(gcnt, 0, NBKT * sizeof(int), stream);

    // setup (weight prep + graph offsets + pooled zero) + edge binning fused:
    // trivial setup blocks finish instantly, bin gets the whole machine.
    setup_bin_kernel<<<NB_SETUP + NB_BIN, 256, 0, stream>>>(
        emb_w, wpe, fc1_w, fc2_w, wpf, batch, goffs, gcnt, pooled,
        src, dst, ebin);

    // embed standalone (r7's bin||embed fusion dragged it 44 -> 74 us)
    const int gemm_blocks = N_NODES / TILE_N;   // 3125
    embed_kernel<<<gemm_blocks, 256, 0, stream>>>(x, wpe, emb_b,
                                                  ibn_g, ibn_b, ibn_m, ibn_v, h0);

    // fused offs + scatter (one ebin read, LDS-staged, 1024 threads/bucket)
    offs_scatter_kernel<<<NBKT, 1024, 0, stream>>>(gcnt, ebin, offs, csr);

    const float* hin = h0;
    float* hout = h1;
    for (int i = 0; i < 3; i++) {
        if (i < 2)
            agg_mlp_kernel<false><<<gemm_blocks, 256, 0, stream>>>(
                hin, hout, offs, csr, batch, pooled,
                wpf + (size_t)(i * 2 + 0) * 8192, wpf + (size_t)(i * 2 + 1) * 8192,
                fc1_b + i * HID, mbn_g + i * HID, mbn_b + i * HID, mbn_m + i * HID, mbn_v + i * HID,
                fc2_b + i * HID, obn_g + i * HID, obn_b + i * HID, obn_m + i * HID, obn_v + i * HID);
        else
            agg_mlp_kernel<true><<<gemm_blocks, 256, 0, stream>>>(
                hin, hout, offs, csr, batch, pooled,
                wpf + (size_t)(i * 2 + 0) * 8192, wpf + (size_t)(i * 2 + 1) * 8192,
                fc1_b + i * HID, mbn_g + i * HID, mbn_b + i * HID, mbn_m + i * HID, mbn_v + i * HID,
                fc2_b + i * HID, obn_g + i * HID, obn_b + i * HID, obn_m + i * HID, obn_v + i * HID);
        const float* tmp = hin; hin = hout; hout = (float*)tmp;
    }

    cls_kernel<<<NGRAPH, 64, 0, stream>>>(pooled, goffs, cls1w, cls1b, cls2w, cls2b,
                                          (float*)d_out);
}